// Round 11
// baseline (133.899 us; speedup 1.0000x reference)
//
#include <hip/hip_runtime.h>
#include <math.h>

// MultiHeadAttention_3728031613617 — bf16-MFMA pipeline v19.
// v19 = prep/proj v11 VERBATIM + flash rebuilt on 32x32x16 MFMA with
// swapped QK^T and in-register P (T12 pattern, shfl_xor primitive):
//   zs = sum_dc mfma32(Kfrag[dc], Qfrag[dc])  ->  lane holds
//   P[key=(r&3)+8(r>>2)+4*l5][q=tx5]: q is lane-resident, so PV's
//   B-operand needs only a lane<->lane+32 exchange: pack pairs to u32,
//   8x shfl_xor(32) + 8 selects. NO LDS in the main loop at all:
//   K/Q/V fragments are direct per-lane 16B global loads (K prefetched
//   one tile ahead in registers — v11/v12 lesson), P never leaves regs.
//   Kills the P round-trip + all 1.57M bank-conflict cycles + K staging.
// Operand-layout basis: this kernel's VERIFIED 16x16x32 loads prove gfx950
// gives each lane 8 CONSECUTIVE k per operand (k=quad*8+e); 32x32x16 is the
// same design with l5: k=l5*8+e. C-layout 32x32 per learn_hip m74/m101.
// Combine: myO re-laid as [v][q] (conflict-free writes, linear reads);
// vob + dense epilogue byte-identical to v11/v15.

typedef __bf16 bf16;
typedef __bf16 bf16x4v __attribute__((ext_vector_type(4)));
typedef __bf16 bf16x8v __attribute__((ext_vector_type(8)));
typedef float f32x4 __attribute__((ext_vector_type(4)));
typedef float f32x16 __attribute__((ext_vector_type(16)));
typedef unsigned int u32x4v __attribute__((ext_vector_type(4)));

namespace {
constexpr int kS = 2048;
constexpr int kD = 512;
constexpr int kRows = 16384;  // 8 * 2048
}

#define MFMA16(a, b, c) __builtin_amdgcn_mfma_f32_16x16x32_bf16((a), (b), (c), 0, 0, 0)
#define MFMA32(a, b, c) __builtin_amdgcn_mfma_f32_32x32x16_bf16((a), (b), (c), 0, 0, 0)

static __device__ __forceinline__ unsigned pk2(float a, float b) {
  unsigned short la = __builtin_bit_cast(unsigned short, (bf16)a);
  unsigned short lb = __builtin_bit_cast(unsigned short, (bf16)b);
  return (unsigned)la | ((unsigned)lb << 16);
}

// ---------------------------------------------------------------------------
// Kernel 0: prep. wtg[mat][n=64][k=512] = (bf16)W[mat][k][n]
//           drt[o=512][j=64] = (bf16) sum_h dense[h*64+j, o]
// ---------------------------------------------------------------------------
__global__ __launch_bounds__(256) void prep_kernel(const float* __restrict__ w,
                                                   const float* __restrict__ dense,
                                                   bf16* __restrict__ wtg,
                                                   bf16* __restrict__ drt) {
  const int bid = blockIdx.x, tid = threadIdx.x;
  __shared__ float T[64][65];  // padded: bank (r*65+c)%32 == (r+c)%32

  if (bid < 24) {
    const int mat = bid >> 3, k0 = (bid & 7) * 64;
#pragma unroll
    for (int p = 0; p < 16; ++p) {
      int e = tid + p * 256;       // 0..4095
      int r = e >> 6, n = e & 63;  // k-row, n
      T[r][n] = w[mat * 32768 + (k0 + r) * 64 + n];
    }
    __syncthreads();
#pragma unroll
    for (int p = 0; p < 16; ++p) {
      int e = tid + p * 256;
      int n = e >> 6, c = e & 63;
      wtg[(size_t)mat * 32768 + (size_t)n * 512 + k0 + c] = (bf16)T[c][n];
    }
  } else {
    const int o0 = (bid - 24) * 64;
    const int oo = tid & 63, jg = tid >> 6;
    float a[16];
#pragma unroll
    for (int i = 0; i < 16; ++i) a[i] = 0.f;
#pragma unroll
    for (int h = 0; h < 8; ++h)
#pragma unroll
      for (int i = 0; i < 16; ++i)
        a[i] += dense[(size_t)(h * 64 + jg * 16 + i) * kD + o0 + oo];
#pragma unroll
    for (int i = 0; i < 16; ++i) T[oo][jg * 16 + i] = a[i];
    __syncthreads();
#pragma unroll
    for (int p = 0; p < 16; ++p) {
      int e = tid + p * 256;
      int r = e >> 6, j = e & 63;
      drt[(size_t)(o0 + r) * 64 + j] = (bf16)T[r][j];
    }
  }
}

// ---------------------------------------------------------------------------
// Kernel 1: fused QKV projection (v11 verbatim). grid 256, block 512.
// ---------------------------------------------------------------------------
__global__ __launch_bounds__(512) void proj_kernel(const float* __restrict__ x,
                                                   const bf16* __restrict__ wtg,
                                                   bf16* __restrict__ wq,
                                                   bf16* __restrict__ wk,
                                                   bf16* __restrict__ wvt) {
  const int bt = blockIdx.x;
  const int tid = threadIdx.x;
  const int w = tid >> 6, tx = tid & 15, quad = (tid >> 4) & 3;
  const int rt = w & 3, nh = w >> 2;
  const int row0 = bt * 64;

  __shared__ bf16 Xs[64 * 72];
  __shared__ bf16 Wts[3 * 64 * 72];

  f32x4 acc[6];
#pragma unroll
  for (int j = 0; j < 6; ++j) acc[j] = (f32x4){0.f, 0.f, 0.f, 0.f};

  const int xr0 = tid >> 4, xc4 = (tid & 15) * 4;
  const float* xb0 = &x[(size_t)(row0 + xr0) * kD + xc4];
  const float* xb1 = &x[(size_t)(row0 + xr0 + 32) * kD + xc4];
  const int wn = tid >> 3, wc8 = (tid & 7) * 8;
  const bf16* wb = &wtg[(size_t)wn * 512 + wc8];

  float4 xf0, xf1;
  uint4 wf0, wf1, wf2;
#define PROJ_ISSUE(K0)                        \
  do {                                        \
    xf0 = *(const float4*)(xb0 + (K0));       \
    xf1 = *(const float4*)(xb1 + (K0));       \
    wf0 = *(const uint4*)(wb + (K0));         \
    wf1 = *(const uint4*)(wb + 32768 + (K0)); \
    wf2 = *(const uint4*)(wb + 65536 + (K0)); \
  } while (0)

  PROJ_ISSUE(0);
  for (int k0 = 0; k0 < kD; k0 += 64) {
    __syncthreads();
    {
      bf16x4v h0 = {(bf16)xf0.x, (bf16)xf0.y, (bf16)xf0.z, (bf16)xf0.w};
      *(bf16x4v*)&Xs[xr0 * 72 + xc4] = h0;
      bf16x4v h1 = {(bf16)xf1.x, (bf16)xf1.y, (bf16)xf1.z, (bf16)xf1.w};
      *(bf16x4v*)&Xs[(xr0 + 32) * 72 + xc4] = h1;
      *(uint4*)&Wts[(0 * 64 + wn) * 72 + wc8] = wf0;
      *(uint4*)&Wts[(1 * 64 + wn) * 72 + wc8] = wf1;
      *(uint4*)&Wts[(2 * 64 + wn) * 72 + wc8] = wf2;
    }
    if (k0 + 64 < kD) PROJ_ISSUE(k0 + 64);
    __syncthreads();
#pragma unroll
    for (int s = 0; s < 2; ++s) {
      bf16x8v a = *(bf16x8v*)&Xs[(rt * 16 + tx) * 72 + s * 32 + quad * 8];
#pragma unroll
      for (int j = 0; j < 6; ++j) {
        int ntg = nh * 6 + j;
        bf16x8v bfr = *(bf16x8v*)&Wts[(ntg * 16 + tx) * 72 + s * 32 + quad * 8];
        acc[j] = MFMA16(a, bfr, acc[j]);
      }
    }
  }

#pragma unroll
  for (int j = 0; j < 6; ++j) {
    int ntg = nh * 6 + j, mat = ntg >> 2, nt = ntg & 3;
    if (mat < 2) {
      bf16* dst = mat ? wk : wq;
#pragma unroll
      for (int r = 0; r < 4; ++r) {
        int row_g = row0 + rt * 16 + quad * 4 + r;
        dst[(size_t)row_g * 64 + nt * 16 + tx] = (bf16)acc[j][r];
      }
    }
  }
  __syncthreads();
  bf16* Vt = Xs;  // [64 v][72] transpose staging for wvt
#pragma unroll
  for (int j = 0; j < 6; ++j) {
    int ntg = nh * 6 + j, mat = ntg >> 2, nt = ntg & 3;
    if (mat == 2) {
#pragma unroll
      for (int r = 0; r < 4; ++r)
        Vt[(nt * 16 + tx) * 72 + rt * 16 + quad * 4 + r] = (bf16)acc[j][r];
    }
  }
  __syncthreads();
  {
    int v = tid >> 3, seg = tid & 7;
    *(uint4*)&wvt[(size_t)v * kRows + row0 + seg * 8] =
        *(uint4*)&Vt[v * 72 + seg * 8];
  }
}

// ---------------------------------------------------------------------------
// Kernel 2: flash attention v19 — 32x32 swapped QK, in-register P, LDS-free
// main loop. grid 512: b = bid&7, qb = bid>>3 (32 Q-rows). Block 512 = 8
// waves; wave w owns key tiles (t*8+w)*32, t<8. LDS only for combine (myO
// now [v=64][q=32] f32: conflict-free writes, linear reads) + vob + dense
// epilogue (all unchanged from v11/v15). LDS 70656 B -> 2 blk/CU. (512,2).
// ---------------------------------------------------------------------------
__global__ __launch_bounds__(512, 2) void flash_kernel(
    const bf16* __restrict__ wq, const bf16* __restrict__ wk,
    const bf16* __restrict__ wvt, const bf16* __restrict__ drt,
    float* __restrict__ out) {
  const int bid = blockIdx.x;
  const int b = bid & 7, qb = bid >> 3;
  const int q0 = qb * 32;
  const int tid = threadIdx.x;
  const int w = tid >> 6, lane = tid & 63, tx = tid & 15, quad = (tid >> 4) & 3;
  const int tx5 = lane & 31, l5 = lane >> 5;
  const bool hi = (l5 != 0);

  __shared__ __align__(16) char lds[65536];   // 8 waves x 8KB combine slots
  __shared__ float Lsh[256];                  // 8 waves x 32 q-rows
  __shared__ __align__(16) bf16 vob[32 * 64]; // combined O, swizzled rows

  const bf16* wqb = wq + (size_t)(b * kS) * 64;
  const bf16* wkb = wk + (size_t)(b * kS) * 64;
  const bf16* wvb = wvt + b * kS;

  const int kc0 = (quad ^ (tx & 7)) * 8;        // vob rows, s=0 chunk
  const int kc1 = ((4 + quad) ^ (tx & 7)) * 8;  // s=1 chunk

  // Per-lane fragment bases (all direct global; 16B contiguous each).
  const bf16* qb5 = wqb + (size_t)(q0 + tx5) * 64 + l5 * 8;
  const bf16* kb5 = wkb + (size_t)tx5 * 64 + l5 * 8;
  const bf16* vb5 = wvb + (size_t)tx5 * kRows + l5 * 8;

  // Q fragments: B-operand (n=q=tx5, k=l5*8+e), d-chunks dc*16.
  bf16x8v aq0 = *(const bf16x8v*)(qb5 + 0);
  bf16x8v aq1 = *(const bf16x8v*)(qb5 + 16);
  bf16x8v aq2 = *(const bf16x8v*)(qb5 + 32);
  bf16x8v aq3 = *(const bf16x8v*)(qb5 + 48);

  f32x16 oacc0 = {0.f, 0.f, 0.f, 0.f, 0.f, 0.f, 0.f, 0.f,
                  0.f, 0.f, 0.f, 0.f, 0.f, 0.f, 0.f, 0.f};
  f32x16 oacc1 = oacc0;
  float lsum = 0.f;

  // K fragments tile 0 (A-operand: m=key=tx5, k=l5*8+e), prefetched ahead.
  bf16x8v ka0 = *(const bf16x8v*)(kb5 + (size_t)(w * 32) * 64 + 0);
  bf16x8v ka1 = *(const bf16x8v*)(kb5 + (size_t)(w * 32) * 64 + 16);
  bf16x8v ka2 = *(const bf16x8v*)(kb5 + (size_t)(w * 32) * 64 + 32);
  bf16x8v ka3 = *(const bf16x8v*)(kb5 + (size_t)(w * 32) * 64 + 48);

#pragma unroll
  for (int t = 0; t < 8; ++t) {
    const int k0 = (t * 8 + w) * 32;

    // Swapped QK^T: zs = sum_dc K[dc]^T-ish... A=K (m=key), B=Q (n=q).
    f32x16 zs = {0.f, 0.f, 0.f, 0.f, 0.f, 0.f, 0.f, 0.f,
                 0.f, 0.f, 0.f, 0.f, 0.f, 0.f, 0.f, 0.f};
    zs = MFMA32(ka0, aq0, zs);
    zs = MFMA32(ka1, aq1, zs);
    zs = MFMA32(ka2, aq2, zs);
    zs = MFMA32(ka3, aq3, zs);

    // Prefetch next tile's K into the same regs (WAR after MFMA issue;
    // consumed next iteration after softmax+PV — full-tile distance).
    if (t < 7) {
      const size_t kn = (size_t)((t + 1) * 8 + w) * 32 * 64;
      ka0 = *(const bf16x8v*)(kb5 + kn + 0);
      ka1 = *(const bf16x8v*)(kb5 + kn + 16);
      ka2 = *(const bf16x8v*)(kb5 + kn + 32);
      ka3 = *(const bf16x8v*)(kb5 + kn + 48);
    }

    // V fragments for this tile (A-operand: m=v=tx5 (+vt*32), k=key
    // l5*8+e within kh*16). Issued before softmax to hide L2 latency.
    bf16x8v vf00 = *(const bf16x8v*)(vb5 + (size_t)0 * kRows + k0 + 0);
    bf16x8v vf01 = *(const bf16x8v*)(vb5 + (size_t)0 * kRows + k0 + 16);
    bf16x8v vf10 = *(const bf16x8v*)(vb5 + (size_t)32 * kRows + k0 + 0);
    bf16x8v vf11 = *(const bf16x8v*)(vb5 + (size_t)32 * kRows + k0 + 16);

    // Softmax numerators. zs reg r holds key (r&3)+8*(r>>2)+4*l5, q=tx5.
    float x0 = __expf(zs[0] * 0.1f), x1 = __expf(zs[1] * 0.1f);
    float x2 = __expf(zs[2] * 0.1f), x3 = __expf(zs[3] * 0.1f);
    float x4 = __expf(zs[4] * 0.1f), x5 = __expf(zs[5] * 0.1f);
    float x6 = __expf(zs[6] * 0.1f), x7 = __expf(zs[7] * 0.1f);
    float x8 = __expf(zs[8] * 0.1f), x9 = __expf(zs[9] * 0.1f);
    float x10 = __expf(zs[10] * 0.1f), x11 = __expf(zs[11] * 0.1f);
    float x12 = __expf(zs[12] * 0.1f), x13 = __expf(zs[13] * 0.1f);
    float x14 = __expf(zs[14] * 0.1f), x15 = __expf(zs[15] * 0.1f);
    lsum += (((x0 + x1) + (x2 + x3)) + ((x4 + x5) + (x6 + x7))) +
            (((x8 + x9) + (x10 + x11)) + ((x12 + x13) + (x14 + x15)));

    // Pack consecutive-key pairs: u_i covers keys per derivation below.
    unsigned u0 = pk2(x0, x1);    // keys 4*l5+0,1
    unsigned u1 = pk2(x2, x3);    // keys 4*l5+2,3
    unsigned u2 = pk2(x4, x5);    // keys 8+4*l5+0,1
    unsigned u3 = pk2(x6, x7);    // keys 8+4*l5+2,3
    unsigned u4 = pk2(x8, x9);    // keys 16+4*l5+0,1
    unsigned u5 = pk2(x10, x11);  // keys 16+4*l5+2,3
    unsigned u6 = pk2(x12, x13);  // keys 24+4*l5+0,1
    unsigned u7 = pk2(x14, x15);  // keys 24+4*l5+2,3

    // Exchange halves (lane <-> lane+32, same tx5) and assemble PV B-frags:
    // pb0 needs keys l5*8+e (kh=0), pb1 needs 16+l5*8+e (kh=1).
    unsigned w0 = __shfl_xor(u0, 32), w1 = __shfl_xor(u1, 32);
    unsigned w2 = __shfl_xor(u2, 32), w3 = __shfl_xor(u3, 32);
    unsigned w4 = __shfl_xor(u4, 32), w5 = __shfl_xor(u5, 32);
    unsigned w6 = __shfl_xor(u6, 32), w7 = __shfl_xor(u7, 32);
    unsigned b0 = hi ? w2 : u0, b1 = hi ? w3 : u1;
    unsigned b2 = hi ? u2 : w0, b3 = hi ? u3 : w1;
    unsigned b4 = hi ? w6 : u4, b5 = hi ? w7 : u5;
    unsigned b6 = hi ? u6 : w4, b7 = hi ? u7 : w5;
    bf16x8v pb0 = __builtin_bit_cast(bf16x8v, (u32x4v){b0, b1, b2, b3});
    bf16x8v pb1 = __builtin_bit_cast(bf16x8v, (u32x4v){b4, b5, b6, b7});

    // PV: O^T[v][q] += V^T-frag * P-frag, two key-halves per tile.
    oacc0 = MFMA32(vf00, pb0, oacc0);
    oacc0 = MFMA32(vf01, pb1, oacc0);
    oacc1 = MFMA32(vf10, pb0, oacc1);
    oacc1 = MFMA32(vf11, pb1, oacc1);
  }

  // ---- cross-wave combine (private 8KB f32 regions, no atomics) ----
  __syncthreads();
  float* myO = (float*)(lds + w * 8192);  // [v=64][q=32] f32 (exactly 8KB)
  float* myL = Lsh + w * 32;
#pragma unroll
  for (int r = 0; r < 16; ++r) {
    int vloc = (r & 3) + 8 * (r >> 2) + 4 * l5;
    myO[vloc * 32 + tx5] = oacc0[r];          // vt=0: conflict-free (32 q)
    myO[(32 + vloc) * 32 + tx5] = oacc1[r];   // vt=1
  }
  {
    float lt2 = lsum + __shfl_xor(lsum, 32);  // both key-halves of this wave
    if (lane < 32) myL[lane] = lt2;           // q = lane
  }
  __syncthreads();

  // combined, normalized O -> vob (bf16, row-swizzled for A-frag reads).
  // myO linear index e = v*32 + q.
#pragma unroll
  for (int p = 0; p < 4; ++p) {
    int e = tid + p * 512;  // 2048 = 64 v x 32 q
    int q = e & 31, v = e >> 5;
    float s = 0.f, lt = 0.f;
#pragma unroll
    for (int wv = 0; wv < 8; ++wv) {
      s += ((const float*)(lds + wv * 8192))[e];
      lt += Lsh[wv * 32 + q];
    }
    vob[q * 64 + (((v >> 3) ^ (q & 7)) * 8) + (v & 7)] = (bf16)(s / lt);
  }
  __syncthreads();

  // ---- fused dense epilogue: out[32 x 512] = vob[32 x 64] @ drt^T ----
  bf16x8v av[2][2];
#pragma unroll
  for (int rt = 0; rt < 2; ++rt) {
    av[rt][0] = *(bf16x8v*)&vob[(rt * 16 + tx) * 64 + kc0];
    av[rt][1] = *(bf16x8v*)&vob[(rt * 16 + tx) * 64 + kc1];
  }

  float* OutS = (float*)lds;  // 32 x 260 f32 = 33280 B (aliases dead slots)
#pragma unroll
  for (int c = 0; c < 2; ++c) {  // two 256-col chunks
    if (c) __syncthreads();      // prior chunk's LDS reads done
#pragma unroll
    for (int i = 0; i < 2; ++i) {
      const int ct = c * 16 + w * 2 + i;  // global 16-col tile
      bf16x8v bd0 =
          *(const bf16x8v*)&drt[(size_t)(ct * 16 + tx) * 64 + quad * 8];
      bf16x8v bd1 =
          *(const bf16x8v*)&drt[(size_t)(ct * 16 + tx) * 64 + 32 + quad * 8];
#pragma unroll
      for (int rt = 0; rt < 2; ++rt) {
        f32x4 z = (f32x4){0.f, 0.f, 0.f, 0.f};
        z = MFMA16(av[rt][0], bd0, z);
        z = MFMA16(av[rt][1], bd1, z);
#pragma unroll
        for (int r = 0; r < 4; ++r)
          OutS[(rt * 16 + quad * 4 + r) * 260 + (w * 2 + i) * 16 + tx] = z[r];
      }
    }
    __syncthreads();
    // coalesced full-row stores: 32 rows x 256 f32 = 1KB contiguous per row
#pragma unroll
    for (int p = 0; p < 4; ++p) {
      int e = tid + p * 512;  // 2048 float4
      int row = e >> 6, seg = e & 63;
      *(float4*)&out[(size_t)(b * kS + q0 + row) * kD + c * 256 + seg * 4] =
          *(float4*)&OutS[row * 260 + seg * 4];
    }
  }
}

extern "C" void kernel_launch(void* const* d_in, const int* in_sizes, int n_in,
                              void* d_out, int out_size, void* d_ws,
                              size_t ws_size, hipStream_t stream) {
  const float* x = (const float*)d_in[0];      // [8,2048,512]
  const float* w = (const float*)d_in[1];      // [3,512,64]
  const float* dense = (const float*)d_in[2];  // [512,512]
  float* out = (float*)d_out;                  // [8,2048,512] fp32

  bf16* wq = (bf16*)d_ws;                // 1,048,576 bf16
  bf16* wk = wq + (size_t)kRows * 64;    // 1,048,576
  bf16* wvt = wk + (size_t)kRows * 64;   // 1,048,576  [64][16384]
  bf16* wtg = wvt + (size_t)kRows * 64;  // 98,304     [3][64][512]
  bf16* drt = wtg + 98304;               // 32,768     [512][64]

  prep_kernel<<<32, 256, 0, stream>>>(w, dense, wtg, drt);
  proj_kernel<<<256, 512, 0, stream>>>(x, wtg, wq, wk, wvt);
  flash_kernel<<<512, 512, 0, stream>>>(wq, wk, wvt, drt, out);
}